// Round 2
// baseline (609.704 us; speedup 1.0000x reference)
//
#include <hip/hip_runtime.h>
#include <hip/hip_bf16.h>
#include <math.h>

typedef __attribute__((ext_vector_type(8))) short short8;
typedef __attribute__((ext_vector_type(4))) float floatx4;

// ---------------------------------------------------------------- helpers
__device__ __forceinline__ void load_lds16(const void* g, void* l) {
  __builtin_amdgcn_global_load_lds(
      (__attribute__((address_space(1))) void*)(g),
      (__attribute__((address_space(3))) void*)(l), 16, 0, 0);
}

#define MFMA16x16x32(a, b, c) __builtin_amdgcn_mfma_f32_16x16x32_bf16((a), (b), (c), 0, 0, 0)
#define BARRIER() __builtin_amdgcn_s_barrier()
#define WAIT_LGKM0() asm volatile("s_waitcnt lgkmcnt(0)" ::: "memory")
#define WAIT_VM4() asm volatile("s_waitcnt vmcnt(4)" ::: "memory")
#define WAIT_VM0() asm volatile("s_waitcnt vmcnt(0)" ::: "memory")
#define SCHED_FENCE() __builtin_amdgcn_sched_barrier(0)

__device__ __forceinline__ float to_f(float x) { return x; }
__device__ __forceinline__ float to_f(__hip_bfloat16 x) { return __bfloat162float(x); }
__device__ __forceinline__ void st_val(float* p, float v) { *p = v; }
__device__ __forceinline__ void st_val(__hip_bfloat16* p, float v) { *p = __float2bfloat16(v); }

// ---------------------------------------------------------------- fp32 -> bf16 elementwise (src)
__global__ __launch_bounds__(256) void cvt_f32_bf16(const float4* __restrict__ in,
                                                    ushort* __restrict__ out) {
  int i = blockIdx.x * 256 + threadIdx.x;
  float4 v = in[i];
  ushort4 o;
  __hip_bfloat16 b0 = __float2bfloat16(v.x);
  __hip_bfloat16 b1 = __float2bfloat16(v.y);
  __hip_bfloat16 b2 = __float2bfloat16(v.z);
  __hip_bfloat16 b3 = __float2bfloat16(v.w);
  o.x = *(ushort*)&b0; o.y = *(ushort*)&b1; o.z = *(ushort*)&b2; o.w = *(ushort*)&b3;
  *(ushort4*)(out + 4 * i) = o;
}

// ---------------------------------------------------------------- concat 3 bias vectors (512 each)
__global__ void concat3(const float* __restrict__ a, const float* __restrict__ b,
                        const float* __restrict__ c, float* __restrict__ o) {
  int i = blockIdx.x * 256 + threadIdx.x;  // 0..1535
  o[i] = i < 512 ? a[i] : (i < 1024 ? b[i - 512] : c[i - 1024]);
}

// ---------------------------------------------------------------- fp32 weights -> bf16 transposed
__global__ void transpose_cvt(const float* __restrict__ in,
                              __hip_bfloat16* __restrict__ out, int R, int C) {
  __shared__ __hip_bfloat16 tile[32][33];
  int bx = blockIdx.x * 32, by = blockIdx.y * 32;
  int tx = threadIdx.x, ty = threadIdx.y;  // (32,8)
  for (int i = ty; i < 32; i += 8)
    tile[i][tx] = __float2bfloat16(in[(size_t)(by + i) * C + bx + tx]);
  __syncthreads();
  for (int i = ty; i < 32; i += 8) out[(size_t)(bx + i) * R + by + tx] = tile[tx][i];
}

// ---------------------------------------------------------------- GEMM: C[M,N] = A[M,K] @ BT[N,K]^T + bias, opt GELU
// 256x256 tile, BK=64, 8 waves (2M x 4N), per-wave 128x64 output (acc[8][4]).
// 8-phase schedule (T3+T4): 4 quadrant-phases per K-tile x 2 dbuf tiles.
//   phase A: ds_read A(i0-3,kk0)+B(all j,kk0); stage (t+1) A-half0 -> other dbuf
//   phase B: ds_read A(i4-7,kk0);              stage (t+1) A-half1 -> other dbuf
//   phase C: ds_read A(i0-3,kk1)+B(all j,kk1); no stage (B-halves still being read)
//   phase D: ds_read A(i4-7,kk1);              stage (t+2) B-half0+1 -> this dbuf
//            (safe: B-reads of tile t retired at phase C's closing barrier)
// Tile-boundary wait: vmcnt(4) (keeps t+2's B loads in flight), vmcnt(0) only
// for the last two tiles. Never drains mid-loop.
// st_16x32 LDS swizzle (T2): byte ^= ((byte>>9)&1)<<5, realized as linear
// global_load_lds dest + pre-swizzled per-lane GLOBAL source + swizzled ds_read.
// LDS: A[2 dbuf][2 half][128 rows][64 kk] = 64 KB @0; B same @65536. Total 128 KB.
__global__ __launch_bounds__(512, 2) void gemm256(
    const __hip_bfloat16* __restrict__ A,
    const __hip_bfloat16* __restrict__ BT,
    const float* __restrict__ bias,
    __hip_bfloat16* __restrict__ C,
    int M, int N, int K, int act, int tiles_x) {
  (void)M;
  __shared__ __align__(16) char sm[131072];
  const int tid = threadIdx.x;
  const int wave = tid >> 6, lane = tid & 63;
  const int quad = lane >> 4, m = lane & 15;
  const int wmi = wave >> 2, wni = wave & 3;
  // bijective XCD-chunked swizzle (grid % 8 == 0 for all call sites)
  const int nwg = gridDim.x;
  const int wg = (blockIdx.x & 7) * (nwg >> 3) + (blockIdx.x >> 3);
  const int row0 = (wg / tiles_x) * 256;
  const int col0 = (wg % tiles_x) * 256;
  const int nt = K >> 6;

  // ---- staging source addressing (pre-swizzled column byte) ----
  // lane covers LDS bytes [chunk + lane*16); row = chunkrow + (lane>>3),
  // swizzle condition (row>>2)&1 == (lane>>5)&1 for 8-row chunks.
  const int colb = ((lane & 7) * 16) ^ (((lane >> 5) & 1) << 5);
  const int rbase = wave * 16 + (lane >> 3);  // rows of chunk r=0; r=1 adds 8
  const char* pA0 = (const char*)(A + (size_t)(row0 + rbase) * K) + colb;
  const char* pA1 = (const char*)(A + (size_t)(row0 + rbase + 8) * K) + colb;
  const char* pA2 = (const char*)(A + (size_t)(row0 + 128 + rbase) * K) + colb;
  const char* pA3 = (const char*)(A + (size_t)(row0 + 128 + rbase + 8) * K) + colb;
  const char* pB0 = (const char*)(BT + (size_t)(col0 + rbase) * K) + colb;
  const char* pB1 = (const char*)(BT + (size_t)(col0 + rbase + 8) * K) + colb;
  const char* pB2 = (const char*)(BT + (size_t)(col0 + 128 + rbase) * K) + colb;
  const char* pB3 = (const char*)(BT + (size_t)(col0 + 128 + rbase + 8) * K) + colb;
  const int c0 = wave * 2048;        // LDS chunk r=0 (wave-uniform)
  const int c1 = wave * 2048 + 1024; // LDS chunk r=1

#define STAGE_A_H0(d)                          \
  do {                                         \
    load_lds16(pA0, sm + (d) + c0);            \
    load_lds16(pA1, sm + (d) + c1);            \
    pA0 += 128; pA1 += 128;                    \
  } while (0)
#define STAGE_A_H1(d)                          \
  do {                                         \
    load_lds16(pA2, sm + (d) + 16384 + c0);    \
    load_lds16(pA3, sm + (d) + 16384 + c1);    \
    pA2 += 128; pA3 += 128;                    \
  } while (0)
#define STAGE_B_H0(d)                              \
  do {                                             \
    load_lds16(pB0, sm + 65536 + (d) + c0);        \
    load_lds16(pB1, sm + 65536 + (d) + c1);        \
    pB0 += 128; pB1 += 128;                        \
  } while (0)
#define STAGE_B_H1(d)                                  \
  do {                                                 \
    load_lds16(pB2, sm + 65536 + (d) + 16384 + c0);    \
    load_lds16(pB3, sm + 65536 + (d) + 16384 + c1);    \
    pB2 += 128; pB3 += 128;                            \
  } while (0)

  // prologue: tile0 all 4 halves (dbuf0) + tile1 B-halves (dbuf1); wait all but 4
  STAGE_A_H0(0); STAGE_A_H1(0); STAGE_B_H0(0); STAGE_B_H1(0);
  STAGE_B_H0(32768); STAGE_B_H1(32768);
  WAIT_VM4();
  BARRIER();

  // ---- ds_read fragment addressing (swizzled) ----
  // logical within-half byte = row*128 + kk*64 + quad*16, row = {i|j}*16 + m
  // swizzle flips bit5 when (row>>2)&1 == (m>>2)&1 (i*16/j*16/64 don't touch bit2)
  const int laneRC = m * 128 + ((quad * 16) ^ (((m >> 2) & 1) << 5));
  const int aB = wmi * 16384 + laneRC;
  const int bB = 65536 + (wni >> 1) * 16384 + (wni & 1) * 8192 + laneRC;

  floatx4 acc[8][4] = {};

  for (int t = 0; t < nt; ++t) {
    const int dA = (t & 1) << 15;   // this tile's dbuf byte offset
    const int dN = dA ^ 32768;      // other dbuf
    const char* As = sm + dA + aB;
    const char* Bs = sm + dA + bB;
    const bool notlast = (t < nt - 1);
    const bool notlast2 = (t < nt - 2);
    short8 af[4], bfr[4];

    // ---------------- phase A: kk0, i 0..3 ----------------
#pragma unroll
    for (int i = 0; i < 4; ++i) af[i] = *(const short8*)(As + i * 2048);
#pragma unroll
    for (int j = 0; j < 4; ++j) bfr[j] = *(const short8*)(Bs + j * 2048);
    if (notlast) STAGE_A_H0(dN);
    BARRIER();
    WAIT_LGKM0();
    SCHED_FENCE();
    __builtin_amdgcn_s_setprio(1);
#pragma unroll
    for (int i = 0; i < 4; ++i)
#pragma unroll
      for (int j = 0; j < 4; ++j) acc[i][j] = MFMA16x16x32(af[i], bfr[j], acc[i][j]);
    __builtin_amdgcn_s_setprio(0);
    BARRIER();

    // ---------------- phase B: kk0, i 4..7 ----------------
#pragma unroll
    for (int i = 0; i < 4; ++i) af[i] = *(const short8*)(As + 8192 + i * 2048);
    if (notlast) STAGE_A_H1(dN);
    BARRIER();
    WAIT_LGKM0();
    SCHED_FENCE();
    __builtin_amdgcn_s_setprio(1);
#pragma unroll
    for (int i = 0; i < 4; ++i)
#pragma unroll
      for (int j = 0; j < 4; ++j) acc[i + 4][j] = MFMA16x16x32(af[i], bfr[j], acc[i + 4][j]);
    __builtin_amdgcn_s_setprio(0);
    BARRIER();

    // ---------------- phase C: kk1, i 0..3 ----------------
#pragma unroll
    for (int i = 0; i < 4; ++i) af[i] = *(const short8*)(As + i * 2048 + 64);
#pragma unroll
    for (int j = 0; j < 4; ++j) bfr[j] = *(const short8*)(Bs + j * 2048 + 64);
    BARRIER();
    WAIT_LGKM0();
    SCHED_FENCE();
    __builtin_amdgcn_s_setprio(1);
#pragma unroll
    for (int i = 0; i < 4; ++i)
#pragma unroll
      for (int j = 0; j < 4; ++j) acc[i][j] = MFMA16x16x32(af[i], bfr[j], acc[i][j]);
    __builtin_amdgcn_s_setprio(0);
    BARRIER();

    // ---------------- phase D: kk1, i 4..7 ----------------
#pragma unroll
    for (int i = 0; i < 4; ++i) af[i] = *(const short8*)(As + 8192 + i * 2048 + 64);
    if (notlast2) { STAGE_B_H0(dA); STAGE_B_H1(dA); }
    BARRIER();
    WAIT_LGKM0();
    SCHED_FENCE();
    __builtin_amdgcn_s_setprio(1);
#pragma unroll
    for (int i = 0; i < 4; ++i)
#pragma unroll
      for (int j = 0; j < 4; ++j) acc[i + 4][j] = MFMA16x16x32(af[i], bfr[j], acc[i + 4][j]);
    __builtin_amdgcn_s_setprio(0);
    // tile-boundary wait: counted (keeps t+2's 4 B-loads in flight); drain at tail
    if (notlast2) { WAIT_VM4(); } else { WAIT_VM0(); }
    BARRIER();
  }

#undef STAGE_A_H0
#undef STAGE_A_H1
#undef STAGE_B_H0
#undef STAGE_B_H1

  // ---------------- epilogue ----------------
#pragma unroll
  for (int j = 0; j < 4; ++j) {
    const int col = col0 + wni * 64 + j * 16 + m;
    const float bj = bias[col];
#pragma unroll
    for (int i = 0; i < 8; ++i) {
      const int rowb = row0 + wmi * 128 + i * 16 + quad * 4;
#pragma unroll
      for (int r = 0; r < 4; ++r) {
        float v = acc[i][j][r] + bj;
        if (act == 1) {
          // tanh-form GELU (overflow-safe)
          float t = 0.7978845608f * (v + 0.044715f * v * v * v);
          float e2 = __expf(-2.0f * fabsf(t));
          float th = (1.0f - e2) / (1.0f + e2);
          th = t < 0.0f ? -th : th;
          v = 0.5f * v * (1.0f + th);
        }
        C[(size_t)(rowb + r) * N + col] = __float2bfloat16(v);
      }
    }
  }
}

// ---------------------------------------------------------------- fused attention per (b,h)
// qkv fused: row stride 1536; q at col h*64, k at 512+h*64, v at 1024+h*64.
__global__ __launch_bounds__(384) void attn_fused(
    const __hip_bfloat16* __restrict__ qkv,
    const float* __restrict__ mat,
    float* __restrict__ scores,
    __hip_bfloat16* __restrict__ ctx) {
  __shared__ __align__(16) __hip_bfloat16 Ks[96 * 72];   // [l_k][d], pad 64->72
  __shared__ __align__(16) __hip_bfloat16 Vt[64 * 104];  // [d][l_k], pad 96->104
  __shared__ __align__(16) __hip_bfloat16 Ps[96 * 104];  // [l_q][l_k], pad 96->104
  const int bh = blockIdx.x;
  const int b = bh >> 3, h = bh & 7;
  const __hip_bfloat16* qb = qkv + (size_t)b * 96 * 1536 + h * 64;
  const __hip_bfloat16* kb = qb + 512;
  const __hip_bfloat16* vb = qb + 1024;
  const int tid = threadIdx.x;

  // stage K [96][64] -> Ks, 16B chunks
  for (int c = tid; c < 768; c += 384) {
    int row = c >> 3, c8 = (c & 7) * 8;
    *(short8*)&Ks[row * 72 + c8] = *(const short8*)(kb + (size_t)row * 1536 + c8);
  }
  // stage V transposed
  {
    int d = tid & 63;
    for (int l = tid >> 6; l < 96; l += 6) Vt[d * 104 + l] = vb[(size_t)l * 1536 + d];
  }
  __syncthreads();

  const int wave = tid >> 6, lane = tid & 63;
  const int quad = lane >> 4, m = lane & 15;

  // phase 1: S = Q K^T (16 rows per wave, N=96, K=64)
  short8 a0 = *(const short8*)(qb + (size_t)(wave * 16 + m) * 1536 + quad * 8);
  short8 a1 = *(const short8*)(qb + (size_t)(wave * 16 + m) * 1536 + 32 + quad * 8);
  floatx4 s[6];
  const size_t mbase = ((size_t)bh * 96 + wave * 16 + quad * 4) * 96 + m;
#pragma unroll
  for (int ct = 0; ct < 6; ++ct) {
    short8 b0 = *(const short8*)&Ks[(ct * 16 + m) * 72 + quad * 8];
    short8 b1 = *(const short8*)&Ks[(ct * 16 + m) * 72 + 32 + quad * 8];
    floatx4 accv = {};
    accv = MFMA16x16x32(a0, b0, accv);
    accv = MFMA16x16x32(a1, b1, accv);
#pragma unroll
    for (int r = 0; r < 4; ++r) {
      float sv = accv[r] * 0.125f * mat[mbase + (size_t)r * 96 + ct * 16];
      accv[r] = sv;
      scores[mbase + (size_t)r * 96 + ct * 16] = sv;
    }
    s[ct] = accv;
  }

  // softmax over each row
#pragma unroll
  for (int r = 0; r < 4; ++r) {
    float mx = s[0][r];
#pragma unroll
    for (int ct = 1; ct < 6; ++ct) mx = fmaxf(mx, s[ct][r]);
#pragma unroll
    for (int dd = 1; dd < 16; dd <<= 1) mx = fmaxf(mx, __shfl_xor(mx, dd, 64));
    float sum = 0.f;
#pragma unroll
    for (int ct = 0; ct < 6; ++ct) {
      float e = __expf(s[ct][r] - mx);
      s[ct][r] = e;
      sum += e;
    }
#pragma unroll
    for (int dd = 1; dd < 16; dd <<= 1) sum += __shfl_xor(sum, dd, 64);
    float inv = 1.0f / sum;
#pragma unroll
    for (int ct = 0; ct < 6; ++ct)
      Ps[(wave * 16 + quad * 4 + r) * 104 + ct * 16 + m] = __float2bfloat16(s[ct][r] * inv);
  }
  __syncthreads();

  // phase 2: O = P V  (K = 96, 3 k-steps of 32)
  floatx4 o[4] = {};
#pragma unroll
  for (int ks = 0; ks < 3; ++ks) {
    short8 pa = *(const short8*)&Ps[(wave * 16 + m) * 104 + ks * 32 + quad * 8];
#pragma unroll
    for (int ct = 0; ct < 4; ++ct) {
      short8 vv = *(const short8*)&Vt[(ct * 16 + m) * 104 + ks * 32 + quad * 8];
      o[ct] = MFMA16x16x32(pa, vv, o[ct]);
    }
  }
  __hip_bfloat16* cb = ctx + (size_t)b * 96 * 512 + h * 64;
#pragma unroll
  for (int ct = 0; ct < 4; ++ct)
#pragma unroll
    for (int r = 0; r < 4; ++r)
      cb[(size_t)(wave * 16 + quad * 4 + r) * 512 + ct * 16 + m] = __float2bfloat16(o[ct][r]);
}

// ---------------------------------------------------------------- residual + LayerNorm, one block per row (D=512)
template <typename RT, typename OT>
__global__ __launch_bounds__(256) void ln_res(
    const __hip_bfloat16* __restrict__ a, const RT* __restrict__ rsd,
    const float* __restrict__ g, const float* __restrict__ be,
    OT* __restrict__ out) {
  const int row = blockIdx.x;
  const int tid = threadIdx.x;
  const size_t base = (size_t)row * 512 + tid * 2;
  float x0 = __bfloat162float(a[base]) + to_f(rsd[base]);
  float x1 = __bfloat162float(a[base + 1]) + to_f(rsd[base + 1]);
  float s = x0 + x1, s2 = x0 * x0 + x1 * x1;
#pragma unroll
  for (int d = 1; d < 64; d <<= 1) {
    s += __shfl_xor(s, d, 64);
    s2 += __shfl_xor(s2, d, 64);
  }
  __shared__ float red[8];
  const int wave = tid >> 6, lane = tid & 63;
  if (lane == 0) {
    red[wave] = s;
    red[4 + wave] = s2;
  }
  __syncthreads();
  s = red[0] + red[1] + red[2] + red[3];
  s2 = red[4] + red[5] + red[6] + red[7];
  const float mean = s * (1.0f / 512.0f);
  const float var = s2 * (1.0f / 512.0f) - mean * mean;
  const float rstd = rsqrtf(var + 1e-5f);
  st_val(out + base, (x0 - mean) * rstd * g[tid * 2] + be[tid * 2]);
  st_val(out + base + 1, (x1 - mean) * rstd * g[tid * 2 + 1] + be[tid * 2 + 1]);
}

// ---------------------------------------------------------------- launch
extern "C" void kernel_launch(void* const* d_in, const int* in_sizes, int n_in,
                              void* d_out, int out_size, void* d_ws, size_t ws_size,
                              hipStream_t stream) {
  (void)in_sizes; (void)n_in; (void)out_size; (void)ws_size;
  typedef const float* cf;
  typedef __hip_bfloat16* bf;
  cf src = (cf)d_in[0];
  cf Wq = (cf)d_in[1];  cf bq = (cf)d_in[2];
  cf Wk = (cf)d_in[3];  cf bk = (cf)d_in[4];
  cf Wv = (cf)d_in[5];  cf bv = (cf)d_in[6];
  cf mat = (cf)d_in[7];
  cf Wo = (cf)d_in[8];  cf bo = (cf)d_in[9];
  cf g1 = (cf)d_in[10]; cf be1 = (cf)d_in[11];
  cf W1 = (cf)d_in[12]; cf b1 = (cf)d_in[13];
  cf W2 = (cf)d_in[14]; cf b2 = (cf)d_in[15];
  cf g2 = (cf)d_in[16]; cf be2 = (cf)d_in[17];

  char* ws = (char*)d_ws;
  const size_t SZ = (size_t)24576 * 512 * 2;  // 25,165,824 B
  bf qkv = (bf)(ws);                  // [24576][1536] bf16 = 3*SZ
  bf ctx = (bf)(ws + 3 * SZ);
  bf hb  = (bf)(ws);                  // FFN hidden [24576][2048] = 4*SZ; qkv+ctx dead by then
  bf srcb = (bf)(ws + 4 * SZ);        // dead after qkv-gemm
  bf tmp = (bf)(ws + 4 * SZ);         // wo out -> ln1; later ffn2 out -> ln2
  bf xb  = (bf)(ws + 5 * SZ);         // post-LN1 x
  char* wt = ws + 6 * SZ;
  bf WqkvT = (bf)(wt);                          // [1536][512] bf16
  bf WoT = (bf)(wt + 1572864);
  bf W1T = (bf)(wt + 1572864 + 524288);         // [2048][512]
  bf W2T = (bf)(wt + 1572864 + 524288 + 2097152);  // [512][2048]
  float* bqkv = (float*)(wt + 1572864 + 524288 + 2097152 + 2097152);

  float* yout = (float*)d_out;
  float* scout = (float*)d_out + 12582912;  // scores after y

  cvt_f32_bf16<<<12288, 256, 0, stream>>>((const float4*)src, (ushort*)srcb);
  concat3<<<6, 256, 0, stream>>>(bq, bk, bv, bqkv);

  dim3 tb(32, 8);
  transpose_cvt<<<dim3(16, 16), tb, 0, stream>>>(Wq, WqkvT, 512, 512);
  transpose_cvt<<<dim3(16, 16), tb, 0, stream>>>(Wk, WqkvT + 512 * 512, 512, 512);
  transpose_cvt<<<dim3(16, 16), tb, 0, stream>>>(Wv, WqkvT + 1024 * 512, 512, 512);
  transpose_cvt<<<dim3(16, 16), tb, 0, stream>>>(Wo, WoT, 512, 512);
  transpose_cvt<<<dim3(64, 16), tb, 0, stream>>>(W1, W1T, 512, 2048);
  transpose_cvt<<<dim3(16, 64), tb, 0, stream>>>(W2, W2T, 2048, 512);

  // 256x256-tile 8-phase GEMMs; tiles_x = N/256, grid = (M/256)*(N/256), all %8==0
  gemm256<<<576, 512, 0, stream>>>(srcb, WqkvT, bqkv, qkv, 24576, 1536, 512, 0, 6);

  attn_fused<<<2048, 384, 0, stream>>>(qkv, mat, scout, ctx);

  gemm256<<<192, 512, 0, stream>>>(ctx, WoT, bo, tmp, 24576, 512, 512, 0, 2);
  ln_res<float, __hip_bfloat16><<<24576, 256, 0, stream>>>(tmp, src, g1, be1, xb);
  gemm256<<<768, 512, 0, stream>>>(xb, W1T, b1, hb, 24576, 2048, 512, 1, 8);
  gemm256<<<192, 512, 0, stream>>>(hb, W2T, b2, tmp, 24576, 512, 2048, 0, 2);
  ln_res<__hip_bfloat16, float><<<24576, 256, 0, stream>>>(tmp, xb, g2, be2, yout);
}